// Round 8
// baseline (271.302 us; speedup 1.0000x reference)
//
#include <hip/hip_runtime.h>
#include <hip/hip_bf16.h>

#define N_NODES 10000
#define N_EDGES 640000
#define CH 128
#define NB 64                // histogram/scatter blocks
#define EPB (N_EDGES / NB)   // 10000 edges per block
#define NCHUNK 40            // ceil(N_NODES/256) scan chunks
#define NPAD 10240           // NCHUNK*256

// ---------------------------------------------------------------------------
// K1: FUSED. Blocks [0,NB): per-block LDS DUAL histogram (count + weighted
// degree, 80 KB) + chunk count-partials. Blocks [NB, NB+157): gemm1 = x@W1^T.
// Block NB+157: conv/fc weight fold.
__global__ __launch_bounds__(256) void fused_hist_gemm(const int* __restrict__ ei,
        const float* __restrict__ ew,
        const float* __restrict__ x, const float* __restrict__ W1,
        int* __restrict__ hist, float* __restrict__ dhist, int* __restrict__ pcs,
        float* __restrict__ out,
        const float* __restrict__ conv_w, const float* __restrict__ conv_b,
        const float* __restrict__ fc_w, const float* __restrict__ fc_b,
        float* __restrict__ vbuf, float* __restrict__ c0) {
    __shared__ __align__(16) char smem[NPAD * 8];    // 80 KB union
    int t = threadIdx.x;
    int bid = blockIdx.x;
    if (bid < NB) {
        // ---- dual histogram path ----
        int* h = (int*)smem;                         // 40 KB counts
        float* hf = (float*)(smem + NPAD * 4);       // 40 KB weighted degree
        for (int i = t; i < 2 * NPAD; i += 256) ((int*)smem)[i] = 0;
        __syncthreads();
        int e0 = bid * EPB;
        for (int i = t; i < EPB; i += 256) {
            int e = e0 + i;
            int c = ei[N_EDGES + e];
            atomicAdd(&h[c], 1);                     // LDS atomics
            atomicAdd(&hf[c], ew[e]);
        }
        __syncthreads();
        for (int i = t; i < N_NODES; i += 256) {
            hist[bid * N_NODES + i] = h[i];
            dhist[bid * N_NODES + i] = hf[i];
        }
        // chunk count partials: wave w handles chunks w, w+4, ...
        int lane = t & 63, wave = t >> 6;
        for (int cch = wave; cch < NCHUNK; cch += 4) {
            int s = h[cch * 256 + lane] + h[cch * 256 + lane + 64]
                  + h[cch * 256 + lane + 128] + h[cch * 256 + lane + 192];
            #pragma unroll
            for (int off = 32; off > 0; off >>= 1) s += __shfl_down(s, off, 64);
            if (lane == 0) pcs[cch * NB + bid] = s;  // chunk-major layout
        }
        return;
    }
    if (bid == NB + (N_NODES + 63) / 64) {
        // ---- conv/fc weight folding ----
        for (int i = t; i <= 384; i += 256) {
            if (i < 384) {
                float s = 0.0f;
                for (int o = 0; o < CH; ++o) s += fc_w[o] * conv_w[o * 384 + i];
                vbuf[i] = s;
            } else {
                float s = fc_b[0];
                for (int o = 0; o < CH; ++o) s += fc_w[o] * conv_b[o];
                *c0 = s;
            }
        }
        return;
    }
    // ---- gemm path: out[m][o] = sum_k x[m][k] * W1[o][k] ----
    float (*As)[68]  = (float(*)[68])smem;
    float (*Ws)[132] = (float(*)[132])(smem + 32 * 68 * sizeof(float));
    int tx = t & 31;
    int ty = t >> 5;
    int row0 = (bid - NB) * 64;
    float acc[8][4] = {};
    for (int k0 = 0; k0 < 128; k0 += 32) {
        #pragma unroll
        for (int i = 0; i < 8; ++i) {
            int idx = t + i * 256;
            int r = idx >> 5, k = idx & 31;
            int gr = row0 + r;
            As[k][r] = (gr < N_NODES) ? x[gr * CH + k0 + k] : 0.0f;
        }
        #pragma unroll
        for (int i = 0; i < 16; ++i) {
            int idx = t + i * 256;
            int o = idx >> 5, k = idx & 31;
            Ws[k][o] = W1[o * CH + k0 + k];
        }
        __syncthreads();
        #pragma unroll
        for (int kk = 0; kk < 32; ++kk) {
            float a[8], w[4];
            #pragma unroll
            for (int j = 0; j < 8; ++j) a[j] = As[kk][ty * 8 + j];
            #pragma unroll
            for (int c = 0; c < 4; ++c) w[c] = Ws[kk][tx * 4 + c];
            #pragma unroll
            for (int j = 0; j < 8; ++j)
                #pragma unroll
                for (int c = 0; c < 4; ++c)
                    acc[j][c] += a[j] * w[c];
        }
        __syncthreads();
    }
    #pragma unroll
    for (int j = 0; j < 8; ++j) {
        int gr = row0 + ty * 8 + j;
        if (gr < N_NODES) {
            float4 v = make_float4(acc[j][0], acc[j][1], acc[j][2], acc[j][3]);
            *reinterpret_cast<float4*>(&out[gr * CH + tx * 4]) = v;
        }
    }
}

// ---------------------------------------------------------------------------
// K2: per-node totals + dinv + global exclusive prefix + cursor conversion.
__global__ __launch_bounds__(256) void bofs_kernel(int* __restrict__ hist,
        const float* __restrict__ dhist, const int* __restrict__ pcs,
        int* __restrict__ tot, int* __restrict__ offs, float* __restrict__ dinv) {
    __shared__ int wred[4];
    __shared__ int wsum[4];
    __shared__ int base_sh;
    int blk = blockIdx.x, t = threadIdx.x;
    int lane = t & 63, wave = t >> 6;
    // --- base = edges into nodes of earlier chunks ---
    int bsum = 0;
    for (int i = t; i < blk * NB; i += 256) bsum += pcs[i];
    #pragma unroll
    for (int off = 32; off > 0; off >>= 1) bsum += __shfl_down(bsum, off, 64);
    if (lane == 0) wred[wave] = bsum;
    __syncthreads();
    if (t == 0) base_sh = wred[0] + wred[1] + wred[2] + wred[3];
    // --- per-node totals (count + weighted degree) over 64 hist rows ---
    int n = blk * 256 + t;
    int v = 0;
    if (n < N_NODES) {
        float dsum = 0.0f;
        #pragma unroll 8
        for (int b = 0; b < NB; ++b) {
            v += hist[b * N_NODES + n];
            dsum += dhist[b * N_NODES + n];
        }
        tot[n] = v;
        dinv[n] = rsqrtf(dsum + 1.0f);            // +1 = self-loop weight
    }
    // --- 256-wide scan (wave scan + wave offsets) ---
    int s = v;
    #pragma unroll
    for (int off = 1; off < 64; off <<= 1) {
        int u = __shfl_up(s, off, 64);
        if (lane >= off) s += u;
    }
    if (lane == 63) wsum[wave] = s;
    __syncthreads();
    int wbase = 0;
    for (int i = 0; i < wave; ++i) wbase += wsum[i];
    if (n < N_NODES) {
        int run = base_sh + wbase + s - v;        // global exclusive prefix
        offs[n] = run;
        for (int b = 0; b < NB; ++b) {
            int h = hist[b * N_NODES + n];
            hist[b * N_NODES + n] = run;          // column -> start cursor
            run += h;
        }
    }
}

// ---------------------------------------------------------------------------
// K3: scatter edges into CSR order via LDS cursors; records carry the fully
// NORMALIZED value dinv[r]*w*dinv[c] (dinv staged in LDS).
__global__ __launch_bounds__(256) void scatter_kernel(const int* __restrict__ ei,
        const float* __restrict__ ew, const float* __restrict__ dinv,
        const int* __restrict__ bofs, int2* __restrict__ erec) {
    __shared__ int cur[N_NODES];                 // 40 KB
    __shared__ float di[N_NODES];                // 40 KB
    int b = blockIdx.x, t = threadIdx.x;
    for (int i = t; i < N_NODES; i += 256) {
        cur[i] = bofs[b * N_NODES + i];
        di[i] = dinv[i];
    }
    __syncthreads();
    int e0 = b * EPB;
    for (int i = t; i < EPB; i += 256) {
        int e = e0 + i;
        int r = ei[e];
        int c = ei[N_EDGES + e];
        float v = di[r] * ew[e] * di[c];
        int p = atomicAdd(&cur[c], 1);           // LDS atomic
        erec[p] = make_int2(r, __float_as_int(v));
    }
}

// ---------------------------------------------------------------------------
// K3b: regroup each CSR segment by SOURCE TILE (src>>11, 5 tiles of 2048).
// All agg groups sweep src tiles in the same order -> instantaneous gather
// working set ~1-2 MB -> L2-resident on every XCD.
__global__ __launch_bounds__(256) void regroup_kernel(const int2* __restrict__ erec,
        const int* __restrict__ offs, const int* __restrict__ cnt,
        int2* __restrict__ erec2) {
    __shared__ int curs[8][5];                   // per-(node, tile) cursor
    int g = threadIdx.x >> 5;                    // node group 0..7
    int l = threadIdx.x & 31;
    int n = blockIdx.x * 8 + g;
    int start = offs[n];
    int num = cnt[n];
    // count per tile
    int c0 = 0, c1 = 0, c2 = 0, c3 = 0;
    for (int i = l; i < num; i += 32) {
        int tl = erec[start + i].x >> 11;
        c0 += (tl == 0); c1 += (tl == 1); c2 += (tl == 2); c3 += (tl == 3);
    }
    #pragma unroll
    for (int off = 16; off > 0; off >>= 1) {
        c0 += __shfl_down(c0, off, 32);
        c1 += __shfl_down(c1, off, 32);
        c2 += __shfl_down(c2, off, 32);
        c3 += __shfl_down(c3, off, 32);
    }
    if (l == 0) {
        curs[g][0] = start;
        curs[g][1] = start + c0;
        curs[g][2] = start + c0 + c1;
        curs[g][3] = start + c0 + c1 + c2;
        curs[g][4] = start + c0 + c1 + c2 + c3;
    }
    __syncthreads();
    // scatter into tile-grouped order (intra-tile order arbitrary)
    for (int i = l; i < num; i += 32) {
        int2 rec = erec[start + i];              // L2-hot (just written)
        int tl = rec.x >> 11;
        int p = atomicAdd(&curs[g][tl], 1);      // LDS atomic
        erec2[p] = rec;
    }
}

// ---------------------------------------------------------------------------
// K4: FUSED agg1 + gemm2, 1024 threads: 8 nodes x 4 sub-streams x 32 lanes.
// Each sub-stream handles every 4th batch-of-8 of its node's segment (batch-
// interleaved -> all streams sweep the same src tile together). Partials
// reduced in LDS. grid=1250 -> 2 blocks/CU = 32 waves/CU (occupancy cap);
// concurrent gather streams 10K -> 40K (4x outstanding misses).
__global__ __launch_bounds__(1024, 8) void agg_gemm_kernel(const float4* __restrict__ xw4,
        const int2* __restrict__ erec, const int* __restrict__ offs,
        const int* __restrict__ cnt, const float* __restrict__ dinv,
        const float4* __restrict__ bias4, const float* __restrict__ W2,
        float* __restrict__ out) {
    __shared__ float4 part[8][4][32];            // 16 KB partial accumulators
    __shared__ float hs[8][128];                 // 4 KB relu'd h1 rows
    int t = threadIdx.x;
    int l = t & 31;                              // channel quad
    int q = (t >> 5) & 3;                        // sub-stream 0..3
    int g = t >> 7;                              // node group 0..7
    int n = blockIdx.x * 8 + g;
    int start = offs[n];
    int num = cnt[n];
    float4 acc = make_float4(0.0f, 0.0f, 0.0f, 0.0f);
    if (q == 0) {                                // self term only in stream 0
        float d = dinv[n];
        float dd = d * d;
        float4 self = xw4[n * 32 + l];
        acc = make_float4(dd * self.x, dd * self.y, dd * self.z, dd * self.w);
    }
    int nbat = num >> 3;
    for (int b = q; b < nbat; b += 4) {          // batch-interleaved quarters
        int s0 = start + b * 8;
        int2 r[8];
        #pragma unroll
        for (int j = 0; j < 8; ++j) r[j] = erec[s0 + j];
        float4 f[8];
        #pragma unroll
        for (int j = 0; j < 8; ++j) f[j] = xw4[r[j].x * 32 + l];
        #pragma unroll
        for (int j = 0; j < 8; ++j) {
            float v = __int_as_float(r[j].y);
            acc.x += v * f[j].x; acc.y += v * f[j].y;
            acc.z += v * f[j].z; acc.w += v * f[j].w;
        }
    }
    if (q == 0) {                                // scalar tail (<8 edges)
        for (int i = start + nbat * 8; i < start + num; ++i) {
            int2 r = erec[i];
            float4 f = xw4[r.x * 32 + l];
            float v = __int_as_float(r.y);
            acc.x += v * f.x; acc.y += v * f.y; acc.z += v * f.z; acc.w += v * f.w;
        }
    }
    part[g][q][l] = acc;
    __syncthreads();
    if (q == 0) {                                // reduce 4 partials + bias + relu
        float4 a0 = part[g][0][l], a1 = part[g][1][l];
        float4 a2 = part[g][2][l], a3 = part[g][3][l];
        float4 bb = bias4[l];
        float4 r;
        r.x = fmaxf(a0.x + a1.x + a2.x + a3.x + bb.x, 0.0f);
        r.y = fmaxf(a0.y + a1.y + a2.y + a3.y + bb.y, 0.0f);
        r.z = fmaxf(a0.z + a1.z + a2.z + a3.z + bb.z, 0.0f);
        r.w = fmaxf(a0.w + a1.w + a2.w + a3.w + bb.w, 0.0f);
        *reinterpret_cast<float4*>(&hs[g][4 * l]) = r;
    }
    __syncthreads();
    // ---- mini-GEMM: 1024 threads = (output channel o, row rw), 1 output each
    int o = t & 127;
    int rw = t >> 7;
    const float4* w4p = reinterpret_cast<const float4*>(&W2[o * CH]);
    const float4* hp  = reinterpret_cast<const float4*>(&hs[rw][0]);
    float a = 0.0f;
    #pragma unroll 8
    for (int k4 = 0; k4 < 32; ++k4) {
        float4 w = w4p[k4];                      // L2-hot W2 row
        float4 h = hp[k4];                       // wave-broadcast LDS read
        a += w.x * h.x + w.y * h.y + w.z * h.z + w.w * h.w;
    }
    out[(blockIdx.x * 8 + rw) * CH + o] = a;
}

// ---------------------------------------------------------------------------
// K5: aggregation layer 2, same 4-sub-stream structure (no gemm).
__global__ __launch_bounds__(1024, 8) void agg_kernel(const float4* __restrict__ xw4,
        const int2* __restrict__ erec, const int* __restrict__ offs,
        const int* __restrict__ cnt, const float* __restrict__ dinv,
        const float4* __restrict__ bias4, float4* __restrict__ out4) {
    __shared__ float4 part[8][4][32];            // 16 KB partial accumulators
    int t = threadIdx.x;
    int l = t & 31;
    int q = (t >> 5) & 3;
    int g = t >> 7;
    int n = blockIdx.x * 8 + g;
    int start = offs[n];
    int num = cnt[n];
    float4 acc = make_float4(0.0f, 0.0f, 0.0f, 0.0f);
    if (q == 0) {
        float d = dinv[n];
        float dd = d * d;
        float4 self = xw4[n * 32 + l];
        acc = make_float4(dd * self.x, dd * self.y, dd * self.z, dd * self.w);
    }
    int nbat = num >> 3;
    for (int b = q; b < nbat; b += 4) {
        int s0 = start + b * 8;
        int2 r[8];
        #pragma unroll
        for (int j = 0; j < 8; ++j) r[j] = erec[s0 + j];
        float4 f[8];
        #pragma unroll
        for (int j = 0; j < 8; ++j) f[j] = xw4[r[j].x * 32 + l];
        #pragma unroll
        for (int j = 0; j < 8; ++j) {
            float v = __int_as_float(r[j].y);
            acc.x += v * f[j].x; acc.y += v * f[j].y;
            acc.z += v * f[j].z; acc.w += v * f[j].w;
        }
    }
    if (q == 0) {
        for (int i = start + nbat * 8; i < start + num; ++i) {
            int2 r = erec[i];
            float4 f = xw4[r.x * 32 + l];
            float v = __int_as_float(r.y);
            acc.x += v * f.x; acc.y += v * f.y; acc.z += v * f.z; acc.w += v * f.w;
        }
    }
    part[g][q][l] = acc;
    __syncthreads();
    if (q == 0) {
        float4 a0 = part[g][0][l], a1 = part[g][1][l];
        float4 a2 = part[g][2][l], a3 = part[g][3][l];
        float4 bb = bias4[l];
        float4 r;
        r.x = fmaxf(a0.x + a1.x + a2.x + a3.x + bb.x, 0.0f);
        r.y = fmaxf(a0.y + a1.y + a2.y + a3.y + bb.y, 0.0f);
        r.z = fmaxf(a0.z + a1.z + a2.z + a3.z + bb.z, 0.0f);
        r.w = fmaxf(a0.w + a1.w + a2.w + a3.w + bb.w, 0.0f);
        out4[n * 32 + l] = r;
    }
}

// ---------------------------------------------------------------------------
// K6: fused temporal conv + fc: one wave per node, lane handles ch l and l+64.
__global__ __launch_bounds__(256) void convfc_kernel(const float* __restrict__ h,
        const float* __restrict__ v, const float* __restrict__ c0,
        float* __restrict__ out, int N) {
    int n = blockIdx.x * 4 + (threadIdx.x >> 6);
    int l = threadIdx.x & 63;
    if (n >= N) return;
    const float* hn = h + n * CH;
    float v0a = v[l * 3 + 0],        v1a = v[l * 3 + 1],        v2a = v[l * 3 + 2];
    float v0b = v[(l + 64) * 3 + 0], v1b = v[(l + 64) * 3 + 1], v2b = v[(l + 64) * 3 + 2];
    float p = hn[l] * v1a + hn[l + 64] * v1b;
    if (n > 0)     p += hn[l - CH] * v0a + hn[l + 64 - CH] * v0b;
    if (n < N - 1) p += hn[l + CH] * v2a + hn[l + 64 + CH] * v2b;
    #pragma unroll
    for (int off = 32; off > 0; off >>= 1) p += __shfl_down(p, off, 64);
    if (l == 0) out[n] = p + *c0;
}

// ---------------------------------------------------------------------------
extern "C" void kernel_launch(void* const* d_in, const int* in_sizes, int n_in,
                              void* d_out, int out_size, void* d_ws, size_t ws_size,
                              hipStream_t stream) {
    const float* x       = (const float*)d_in[0];
    const int*   ei      = (const int*)d_in[1];
    const float* ew      = (const float*)d_in[2];
    const float* W1      = (const float*)d_in[3];
    const float* b1      = (const float*)d_in[4];
    const float* W2      = (const float*)d_in[5];
    const float* b2      = (const float*)d_in[6];
    const float* conv_w  = (const float*)d_in[7];
    const float* conv_b  = (const float*)d_in[8];
    const float* fc_w    = (const float*)d_in[9];
    const float* fc_b    = (const float*)d_in[10];
    float* out = (float*)d_out;

    float* bufA   = (float*)d_ws;                   // 1,280,000 f (xw1, later h2)
    float* bufB   = bufA + N_NODES * CH;            // 1,280,000 f (xw2)
    int2*  erec   = (int2*)(bufB + N_NODES * CH);   // 640,000 x 8B (scatter order)
    int2*  erec2  = erec + N_EDGES;                 // 640,000 x 8B (tile-grouped)
    int*   hist   = (int*)(erec2 + N_EDGES);        // NB*10,000 i
    float* dhist  = (float*)(hist + NB * N_NODES);  // NB*10,000 f
    int*   pcs    = (int*)(dhist + NB * N_NODES);   // NCHUNK*NB i
    int*   tot    = pcs + NCHUNK * NB;              // 10,000 i
    int*   offs   = tot + N_NODES;                  // 10,000 i
    float* dinv   = (float*)(offs + N_NODES);       // 10,000 f
    float* vbuf   = dinv + N_NODES;                 // 384 f
    float* c0     = vbuf + 384;                     // 1 f

    const int gemm_grid = (N_NODES + 63) / 64;      // 157

    // K1: dual-hist (64) + gemm1 (157) + weight-fold (1), all data-independent
    fused_hist_gemm<<<NB + gemm_grid + 1, 256, 0, stream>>>(ei, ew, x, W1,
            hist, dhist, pcs, bufA, conv_w, conv_b, fc_w, fc_b, vbuf, c0);
    // K2: totals + dinv + prefix + cursor conversion
    bofs_kernel<<<NCHUNK, 256, 0, stream>>>(hist, dhist, pcs, tot, offs, dinv);
    // K3: normalized CSR scatter
    scatter_kernel<<<NB, 256, 0, stream>>>(ei, ew, dinv, hist, erec);
    // K3b: regroup segments by source tile -> erec2 (L2-sweep locality)
    regroup_kernel<<<N_NODES / 8, 256, 0, stream>>>(erec, offs, tot, erec2);
    // K4: agg1 + gemm2 fused, 4 sub-streams/node: bufA -> bufB
    agg_gemm_kernel<<<N_NODES / 8, 1024, 0, stream>>>((const float4*)bufA, erec2, offs,
            tot, dinv, (const float4*)b1, W2, bufB);
    // K5: agg layer 2, 4 sub-streams/node: bufB -> bufA
    agg_kernel<<<N_NODES / 8, 1024, 0, stream>>>((const float4*)bufB, erec2, offs, tot,
                                                 dinv, (const float4*)b2, (float4*)bufA);
    // K6: fused temporal conv + fc
    convfc_kernel<<<(N_NODES + 3) / 4, 256, 0, stream>>>(bufA, vbuf, c0, out, N_NODES);
}

// Round 9
// 217.326 us; speedup vs baseline: 1.2484x; 1.2484x over previous
//
#include <hip/hip_runtime.h>
#include <hip/hip_bf16.h>

#define N_NODES 10000
#define N_EDGES 640000
#define CH 128
#define NB 64                // histogram/scatter blocks
#define EPB (N_EDGES / NB)   // 10000 edges per block
#define NCHUNK 40            // ceil(N_NODES/256) scan chunks
#define NPAD 10240           // NCHUNK*256
#define G1A 78               // gemm1 blocks co-launched with hist  (rows 0..4991)
#define G1B 79               // gemm1 blocks co-launched with bofs  (rows 4992..9999)

// ---------------------------------------------------------------------------
// Shared GEMM body: out[m][o] = sum_k A[m][k] * W[o][k], 64 rows per block.
__device__ __forceinline__ void gemm128_body(const float* __restrict__ A,
        const float* __restrict__ W, float* __restrict__ out, int row0,
        char* smem) {
    float (*As)[68]  = (float(*)[68])smem;                         //  8704 B
    float (*Ws)[132] = (float(*)[132])(smem + 32 * 68 * sizeof(float)); // 16896 B
    int t = threadIdx.x;
    int tx = t & 31;
    int ty = t >> 5;
    float acc[8][4] = {};
    for (int k0 = 0; k0 < 128; k0 += 32) {
        #pragma unroll
        for (int i = 0; i < 8; ++i) {
            int idx = t + i * 256;
            int r = idx >> 5, k = idx & 31;
            int gr = row0 + r;
            As[k][r] = (gr < N_NODES) ? A[gr * CH + k0 + k] : 0.0f;
        }
        #pragma unroll
        for (int i = 0; i < 16; ++i) {
            int idx = t + i * 256;
            int o = idx >> 5, k = idx & 31;
            Ws[k][o] = W[o * CH + k0 + k];
        }
        __syncthreads();
        #pragma unroll
        for (int kk = 0; kk < 32; ++kk) {
            float a[8], w[4];
            #pragma unroll
            for (int j = 0; j < 8; ++j) a[j] = As[kk][ty * 8 + j];
            #pragma unroll
            for (int c = 0; c < 4; ++c) w[c] = Ws[kk][tx * 4 + c];
            #pragma unroll
            for (int j = 0; j < 8; ++j)
                #pragma unroll
                for (int c = 0; c < 4; ++c)
                    acc[j][c] += a[j] * w[c];
        }
        __syncthreads();
    }
    #pragma unroll
    for (int j = 0; j < 8; ++j) {
        int gr = row0 + ty * 8 + j;
        if (gr < N_NODES) {
            float4 v = make_float4(acc[j][0], acc[j][1], acc[j][2], acc[j][3]);
            *reinterpret_cast<float4*>(&out[gr * CH + tx * 4]) = v;
        }
    }
}

// ---------------------------------------------------------------------------
// K1: blocks [0,NB): dual LDS histogram (count + weighted degree, 80 KB) +
// chunk count-partials. Blocks [NB, NB+G1A): gemm1 rows 0..4991.
__global__ __launch_bounds__(256) void hist_gemm_kernel(const int* __restrict__ ei,
        const float* __restrict__ ew, const float* __restrict__ x,
        const float* __restrict__ W1, int* __restrict__ hist,
        float* __restrict__ dhist, int* __restrict__ pcs, float* __restrict__ out) {
    __shared__ __align__(16) char smem[NPAD * 8];    // 80 KB union
    int t = threadIdx.x;
    int bid = blockIdx.x;
    if (bid < NB) {
        int* h = (int*)smem;                         // 40 KB counts
        float* hf = (float*)(smem + NPAD * 4);       // 40 KB weighted degree
        for (int i = t; i < 2 * NPAD; i += 256) ((int*)smem)[i] = 0;
        __syncthreads();
        int e0 = bid * EPB;
        for (int i = t; i < EPB; i += 256) {
            int e = e0 + i;
            int c = ei[N_EDGES + e];
            atomicAdd(&h[c], 1);                     // LDS atomics
            atomicAdd(&hf[c], ew[e]);
        }
        __syncthreads();
        for (int i = t; i < N_NODES; i += 256) {
            hist[bid * N_NODES + i] = h[i];
            dhist[bid * N_NODES + i] = hf[i];
        }
        int lane = t & 63, wave = t >> 6;
        for (int cch = wave; cch < NCHUNK; cch += 4) {
            int s = h[cch * 256 + lane] + h[cch * 256 + lane + 64]
                  + h[cch * 256 + lane + 128] + h[cch * 256 + lane + 192];
            #pragma unroll
            for (int off = 32; off > 0; off >>= 1) s += __shfl_down(s, off, 64);
            if (lane == 0) pcs[cch * NB + bid] = s;  // chunk-major layout
        }
        return;
    }
    gemm128_body(x, W1, out, (bid - NB) * 64, smem);
}

// ---------------------------------------------------------------------------
// K2: blocks [0,NCHUNK): bofs (totals + dinv + prefix + cursor conversion,
// ILP-4 column walk). Blocks [NCHUNK, NCHUNK+G1B): gemm1 rows 4992..9999.
// Block NCHUNK+G1B: conv/fc weight fold.
__global__ __launch_bounds__(256) void bofs_gemm_kernel(int* __restrict__ hist,
        const float* __restrict__ dhist, const int* __restrict__ pcs,
        int* __restrict__ tot, int* __restrict__ offs, float* __restrict__ dinv,
        const float* __restrict__ x, const float* __restrict__ W1,
        float* __restrict__ out,
        const float* __restrict__ conv_w, const float* __restrict__ conv_b,
        const float* __restrict__ fc_w, const float* __restrict__ fc_b,
        float* __restrict__ vbuf, float* __restrict__ c0) {
    __shared__ __align__(16) char smem[32 * 68 * 4 + 32 * 132 * 4];
    int bid = blockIdx.x, t = threadIdx.x;
    if (bid < NCHUNK) {
        int* wred = (int*)smem;                      // [4]
        int* wsum = (int*)smem + 4;                  // [4]
        int* base_sh = (int*)smem + 8;               // [1]
        int lane = t & 63, wave = t >> 6;
        // --- base = edges into nodes of earlier chunks ---
        int bsum = 0;
        for (int i = t; i < bid * NB; i += 256) bsum += pcs[i];
        #pragma unroll
        for (int off = 32; off > 0; off >>= 1) bsum += __shfl_down(bsum, off, 64);
        if (lane == 0) wred[wave] = bsum;
        __syncthreads();
        if (t == 0) *base_sh = wred[0] + wred[1] + wred[2] + wred[3];
        // --- per-node totals (count + weighted degree), ILP-4 ---
        int n = bid * 256 + t;
        int v = 0;
        if (n < N_NODES) {
            float dsum = 0.0f;
            for (int b = 0; b < NB; b += 4) {
                int a0 = hist[(b + 0) * N_NODES + n];
                int a1 = hist[(b + 1) * N_NODES + n];
                int a2 = hist[(b + 2) * N_NODES + n];
                int a3 = hist[(b + 3) * N_NODES + n];
                float f0 = dhist[(b + 0) * N_NODES + n];
                float f1 = dhist[(b + 1) * N_NODES + n];
                float f2 = dhist[(b + 2) * N_NODES + n];
                float f3 = dhist[(b + 3) * N_NODES + n];
                v += a0 + a1 + a2 + a3;
                dsum += f0 + f1 + f2 + f3;
            }
            tot[n] = v;
            dinv[n] = rsqrtf(dsum + 1.0f);           // +1 = self-loop weight
        }
        // --- 256-wide scan ---
        int s = v;
        #pragma unroll
        for (int off = 1; off < 64; off <<= 1) {
            int u = __shfl_up(s, off, 64);
            if (lane >= off) s += u;
        }
        if (lane == 63) wsum[wave] = s;
        __syncthreads();
        int wbase = 0;
        for (int i = 0; i < wave; ++i) wbase += wsum[i];
        if (n < N_NODES) {
            int run = *base_sh + wbase + s - v;      // global exclusive prefix
            offs[n] = run;
            for (int b = 0; b < NB; b += 4) {        // ILP-4 cursor walk
                int h0 = hist[(b + 0) * N_NODES + n];
                int h1 = hist[(b + 1) * N_NODES + n];
                int h2 = hist[(b + 2) * N_NODES + n];
                int h3 = hist[(b + 3) * N_NODES + n];
                hist[(b + 0) * N_NODES + n] = run;
                hist[(b + 1) * N_NODES + n] = run + h0;
                hist[(b + 2) * N_NODES + n] = run + h0 + h1;
                hist[(b + 3) * N_NODES + n] = run + h0 + h1 + h2;
                run += h0 + h1 + h2 + h3;
            }
        }
        return;
    }
    if (bid == NCHUNK + G1B) {
        // ---- conv/fc weight folding ----
        for (int i = t; i <= 384; i += 256) {
            if (i < 384) {
                float s = 0.0f;
                for (int o = 0; o < CH; ++o) s += fc_w[o] * conv_w[o * 384 + i];
                vbuf[i] = s;
            } else {
                float s = fc_b[0];
                for (int o = 0; o < CH; ++o) s += fc_w[o] * conv_b[o];
                *c0 = s;
            }
        }
        return;
    }
    gemm128_body(x, W1, out, 4992 + (bid - NCHUNK) * 64, smem);
}

// ---------------------------------------------------------------------------
// K3: scatter edges into CSR order via LDS cursors; records carry the fully
// NORMALIZED value dinv[r]*w*dinv[c] (dinv staged in LDS).
__global__ __launch_bounds__(256) void scatter_kernel(const int* __restrict__ ei,
        const float* __restrict__ ew, const float* __restrict__ dinv,
        const int* __restrict__ bofs, int2* __restrict__ erec) {
    __shared__ int cur[N_NODES];                 // 40 KB
    __shared__ float di[N_NODES];                // 40 KB
    int b = blockIdx.x, t = threadIdx.x;
    for (int i = t; i < N_NODES; i += 256) {
        cur[i] = bofs[b * N_NODES + i];
        di[i] = dinv[i];
    }
    __syncthreads();
    int e0 = b * EPB;
    for (int i = t; i < EPB; i += 256) {
        int e = e0 + i;
        int r = ei[e];
        int c = ei[N_EDGES + e];
        float v = di[r] * ew[e] * di[c];
        int p = atomicAdd(&cur[c], 1);           // LDS atomic
        erec[p] = make_int2(r, __float_as_int(v));
    }
}

// ---------------------------------------------------------------------------
// K4: FUSED agg1 + gemm2 — round-4 proven structure, UNCHANGED (control).
__global__ __launch_bounds__(256) void agg_gemm_kernel(const float4* __restrict__ xw4,
        const int2* __restrict__ erec, const int* __restrict__ offs,
        const int* __restrict__ cnt, const float* __restrict__ dinv,
        const float4* __restrict__ bias4, const float* __restrict__ W2,
        float* __restrict__ out) {
    __shared__ float hs[8][128];                 // 4 KB relu'd h1 rows
    int l = threadIdx.x & 31;                    // channel quad
    int g = threadIdx.x >> 5;                    // node group 0..7
    int n = blockIdx.x * 8 + g;
    float d = dinv[n];
    float dd = d * d;
    float4 self = xw4[n * 32 + l];
    float4 acc = make_float4(dd * self.x, dd * self.y, dd * self.z, dd * self.w);
    int start = offs[n];
    int num = cnt[n];
    int i = 0;
    for (; i + 8 <= num; i += 8) {
        int2 r[8];
        #pragma unroll
        for (int j = 0; j < 8; ++j) r[j] = erec[start + i + j];
        float4 f[8];
        #pragma unroll
        for (int j = 0; j < 8; ++j) f[j] = xw4[r[j].x * 32 + l];
        #pragma unroll
        for (int j = 0; j < 8; ++j) {
            float v = __int_as_float(r[j].y);
            acc.x += v * f[j].x; acc.y += v * f[j].y;
            acc.z += v * f[j].z; acc.w += v * f[j].w;
        }
    }
    for (; i < num; ++i) {
        int2 r = erec[start + i];
        float4 f = xw4[r.x * 32 + l];
        float v = __int_as_float(r.y);
        acc.x += v * f.x; acc.y += v * f.y; acc.z += v * f.z; acc.w += v * f.w;
    }
    float4 bb = bias4[l];
    acc.x = fmaxf(acc.x + bb.x, 0.0f);
    acc.y = fmaxf(acc.y + bb.y, 0.0f);
    acc.z = fmaxf(acc.z + bb.z, 0.0f);
    acc.w = fmaxf(acc.w + bb.w, 0.0f);
    *reinterpret_cast<float4*>(&hs[g][4 * l]) = acc;
    __syncthreads();
    // ---- mini-GEMM: thread = (output channel o, row-group rg of 4 rows) ----
    int o = threadIdx.x & 127;
    int rg = threadIdx.x >> 7;                   // 0: rows 0-3, 1: rows 4-7
    const float4* w4p = reinterpret_cast<const float4*>(&W2[o * CH]);
    const float4* h0p = reinterpret_cast<const float4*>(&hs[rg * 4 + 0][0]);
    const float4* h1p = reinterpret_cast<const float4*>(&hs[rg * 4 + 1][0]);
    const float4* h2p = reinterpret_cast<const float4*>(&hs[rg * 4 + 2][0]);
    const float4* h3p = reinterpret_cast<const float4*>(&hs[rg * 4 + 3][0]);
    float a0 = 0.0f, a1 = 0.0f, a2 = 0.0f, a3 = 0.0f;
    #pragma unroll 8
    for (int k4 = 0; k4 < 32; ++k4) {
        float4 w = w4p[k4];                      // L2-hot W2 row
        float4 h0 = h0p[k4], h1 = h1p[k4], h2 = h2p[k4], h3 = h3p[k4];
        a0 += w.x * h0.x + w.y * h0.y + w.z * h0.z + w.w * h0.w;
        a1 += w.x * h1.x + w.y * h1.y + w.z * h1.z + w.w * h1.w;
        a2 += w.x * h2.x + w.y * h2.y + w.z * h2.z + w.w * h2.w;
        a3 += w.x * h3.x + w.y * h3.y + w.z * h3.z + w.w * h3.w;
    }
    int nb = blockIdx.x * 8 + rg * 4;
    out[(nb + 0) * CH + o] = a0;
    out[(nb + 1) * CH + o] = a1;
    out[(nb + 2) * CH + o] = a2;
    out[(nb + 3) * CH + o] = a3;
}

// ---------------------------------------------------------------------------
// K5: agg layer 2 — EXPERIMENT: coalesced record loads. One 256 B coalesced
// load per 32 edges (lane l takes record l), distributed via __shfl — removes
// the 8 broadcast loads/batch from the L2 request stream and takes record
// latency off the per-batch dependency chain.
__global__ __launch_bounds__(256) void agg_kernel(const float4* __restrict__ xw4,
        const int2* __restrict__ erec, const int* __restrict__ offs,
        const int* __restrict__ cnt, const float* __restrict__ dinv,
        const float4* __restrict__ bias4, float4* __restrict__ out4) {
    int l = threadIdx.x & 31;
    int g = threadIdx.x >> 5;
    int n = blockIdx.x * 8 + g;
    float d = dinv[n];
    float dd = d * d;
    float4 self = xw4[n * 32 + l];
    float4 acc = make_float4(dd * self.x, dd * self.y, dd * self.z, dd * self.w);
    int start = offs[n];
    int num = cnt[n];
    int i = 0;
    for (; i + 32 <= num; i += 32) {
        int2 my = erec[start + i + l];           // coalesced 256 B per group
        float myv = __int_as_float(my.y);
        #pragma unroll
        for (int jb = 0; jb < 32; jb += 8) {
            int rx[8]; float rv[8];
            #pragma unroll
            for (int k = 0; k < 8; ++k) {
                rx[k] = __shfl(my.x, jb + k, 32);
                rv[k] = __shfl(myv,  jb + k, 32);
            }
            float4 f[8];
            #pragma unroll
            for (int k = 0; k < 8; ++k) f[k] = xw4[rx[k] * 32 + l];
            #pragma unroll
            for (int k = 0; k < 8; ++k) {
                acc.x += rv[k] * f[k].x; acc.y += rv[k] * f[k].y;
                acc.z += rv[k] * f[k].z; acc.w += rv[k] * f[k].w;
            }
        }
    }
    for (; i + 8 <= num; i += 8) {               // 8-deep cleanup (round-4 style)
        int2 r[8];
        #pragma unroll
        for (int j = 0; j < 8; ++j) r[j] = erec[start + i + j];
        float4 f[8];
        #pragma unroll
        for (int j = 0; j < 8; ++j) f[j] = xw4[r[j].x * 32 + l];
        #pragma unroll
        for (int j = 0; j < 8; ++j) {
            float v = __int_as_float(r[j].y);
            acc.x += v * f[j].x; acc.y += v * f[j].y;
            acc.z += v * f[j].z; acc.w += v * f[j].w;
        }
    }
    for (; i < num; ++i) {
        int2 r = erec[start + i];
        float4 f = xw4[r.x * 32 + l];
        float v = __int_as_float(r.y);
        acc.x += v * f.x; acc.y += v * f.y; acc.z += v * f.z; acc.w += v * f.w;
    }
    float4 bb = bias4[l];
    acc.x = fmaxf(acc.x + bb.x, 0.0f);
    acc.y = fmaxf(acc.y + bb.y, 0.0f);
    acc.z = fmaxf(acc.z + bb.z, 0.0f);
    acc.w = fmaxf(acc.w + bb.w, 0.0f);
    out4[n * 32 + l] = acc;
}

// ---------------------------------------------------------------------------
// K6: fused temporal conv + fc: one wave per node, lane handles ch l and l+64.
__global__ __launch_bounds__(256) void convfc_kernel(const float* __restrict__ h,
        const float* __restrict__ v, const float* __restrict__ c0,
        float* __restrict__ out, int N) {
    int n = blockIdx.x * 4 + (threadIdx.x >> 6);
    int l = threadIdx.x & 63;
    if (n >= N) return;
    const float* hn = h + n * CH;
    float v0a = v[l * 3 + 0],        v1a = v[l * 3 + 1],        v2a = v[l * 3 + 2];
    float v0b = v[(l + 64) * 3 + 0], v1b = v[(l + 64) * 3 + 1], v2b = v[(l + 64) * 3 + 2];
    float p = hn[l] * v1a + hn[l + 64] * v1b;
    if (n > 0)     p += hn[l - CH] * v0a + hn[l + 64 - CH] * v0b;
    if (n < N - 1) p += hn[l + CH] * v2a + hn[l + 64 + CH] * v2b;
    #pragma unroll
    for (int off = 32; off > 0; off >>= 1) p += __shfl_down(p, off, 64);
    if (l == 0) out[n] = p + *c0;
}

// ---------------------------------------------------------------------------
extern "C" void kernel_launch(void* const* d_in, const int* in_sizes, int n_in,
                              void* d_out, int out_size, void* d_ws, size_t ws_size,
                              hipStream_t stream) {
    const float* x       = (const float*)d_in[0];
    const int*   ei      = (const int*)d_in[1];
    const float* ew      = (const float*)d_in[2];
    const float* W1      = (const float*)d_in[3];
    const float* b1      = (const float*)d_in[4];
    const float* W2      = (const float*)d_in[5];
    const float* b2      = (const float*)d_in[6];
    const float* conv_w  = (const float*)d_in[7];
    const float* conv_b  = (const float*)d_in[8];
    const float* fc_w    = (const float*)d_in[9];
    const float* fc_b    = (const float*)d_in[10];
    float* out = (float*)d_out;

    float* bufA   = (float*)d_ws;                   // 1,280,000 f (xw1, later h2)
    float* bufB   = bufA + N_NODES * CH;            // 1,280,000 f (xw2)
    int2*  erec   = (int2*)(bufB + N_NODES * CH);   // 640,000 x 8B
    int*   hist   = (int*)(erec + N_EDGES);         // NB*10,000 i
    float* dhist  = (float*)(hist + NB * N_NODES);  // NB*10,000 f
    int*   pcs    = (int*)(dhist + NB * N_NODES);   // NCHUNK*NB i
    int*   tot    = pcs + NCHUNK * NB;              // 10,000 i
    int*   offs   = tot + N_NODES;                  // 10,000 i
    float* dinv   = (float*)(offs + N_NODES);       // 10,000 f
    float* vbuf   = dinv + N_NODES;                 // 384 f
    float* c0     = vbuf + 384;                     // 1 f

    // K1: dual-hist (64) || gemm1 rows 0..4991 (78)
    hist_gemm_kernel<<<NB + G1A, 256, 0, stream>>>(ei, ew, x, W1, hist, dhist,
                                                   pcs, bufA);
    // K2: bofs (40) || gemm1 rows 4992..9999 (79) || weight-fold (1)
    bofs_gemm_kernel<<<NCHUNK + G1B + 1, 256, 0, stream>>>(hist, dhist, pcs, tot,
            offs, dinv, x, W1, bufA, conv_w, conv_b, fc_w, fc_b, vbuf, c0);
    // K3: normalized CSR scatter
    scatter_kernel<<<NB, 256, 0, stream>>>(ei, ew, dinv, hist, erec);
    // K4: agg1 + gemm2 fused (round-4 control): bufA -> bufB
    agg_gemm_kernel<<<N_NODES / 8, 256, 0, stream>>>((const float4*)bufA, erec, offs,
            tot, dinv, (const float4*)b1, W2, bufB);
    // K5: agg layer 2 (coalesced-record experiment): bufB -> bufA
    agg_kernel<<<N_NODES / 8, 256, 0, stream>>>((const float4*)bufB, erec, offs, tot,
                                                dinv, (const float4*)b2, (float4*)bufA);
    // K6: fused temporal conv + fc
    convfc_kernel<<<(N_NODES + 3) / 4, 256, 0, stream>>>(bufA, vbuf, c0, out, N_NODES);
}

// Round 10
// 202.265 us; speedup vs baseline: 1.3413x; 1.0745x over previous
//
#include <hip/hip_runtime.h>
#include <hip/hip_bf16.h>

#define N_NODES 10000
#define N_EDGES 640000
#define CH 128
#define NB 64                // histogram/scatter blocks
#define EPB (N_EDGES / NB)   // 10000 edges per block
#define NCHUNK 40            // ceil(N_NODES/256) scan chunks
#define NPAD 10240           // NCHUNK*256

typedef float f32x4 __attribute__((ext_vector_type(4)));

// ---------------------------------------------------------------------------
// K1: FUSED. Blocks [0,NB): per-block LDS DUAL histogram (count + weighted
// degree, 80 KB) + chunk count-partials. Blocks [NB, NB+157): gemm1 = x@W1^T.
// Block NB+157: conv/fc weight fold.  (round-4 proven, verbatim)
__global__ __launch_bounds__(256) void fused_hist_gemm(const int* __restrict__ ei,
        const float* __restrict__ ew,
        const float* __restrict__ x, const float* __restrict__ W1,
        int* __restrict__ hist, float* __restrict__ dhist, int* __restrict__ pcs,
        float* __restrict__ out,
        const float* __restrict__ conv_w, const float* __restrict__ conv_b,
        const float* __restrict__ fc_w, const float* __restrict__ fc_b,
        float* __restrict__ vbuf, float* __restrict__ c0) {
    __shared__ __align__(16) char smem[NPAD * 8];    // 80 KB union
    int t = threadIdx.x;
    int bid = blockIdx.x;
    if (bid < NB) {
        int* h = (int*)smem;                         // 40 KB counts
        float* hf = (float*)(smem + NPAD * 4);       // 40 KB weighted degree
        for (int i = t; i < 2 * NPAD; i += 256) ((int*)smem)[i] = 0;
        __syncthreads();
        int e0 = bid * EPB;
        for (int i = t; i < EPB; i += 256) {
            int e = e0 + i;
            int c = ei[N_EDGES + e];
            atomicAdd(&h[c], 1);                     // LDS atomics
            atomicAdd(&hf[c], ew[e]);
        }
        __syncthreads();
        for (int i = t; i < N_NODES; i += 256) {
            hist[bid * N_NODES + i] = h[i];
            dhist[bid * N_NODES + i] = hf[i];
        }
        int lane = t & 63, wave = t >> 6;
        for (int cch = wave; cch < NCHUNK; cch += 4) {
            int s = h[cch * 256 + lane] + h[cch * 256 + lane + 64]
                  + h[cch * 256 + lane + 128] + h[cch * 256 + lane + 192];
            #pragma unroll
            for (int off = 32; off > 0; off >>= 1) s += __shfl_down(s, off, 64);
            if (lane == 0) pcs[cch * NB + bid] = s;  // chunk-major layout
        }
        return;
    }
    if (bid == NB + (N_NODES + 63) / 64) {
        for (int i = t; i <= 384; i += 256) {
            if (i < 384) {
                float s = 0.0f;
                for (int o = 0; o < CH; ++o) s += fc_w[o] * conv_w[o * 384 + i];
                vbuf[i] = s;
            } else {
                float s = fc_b[0];
                for (int o = 0; o < CH; ++o) s += fc_w[o] * conv_b[o];
                *c0 = s;
            }
        }
        return;
    }
    // ---- gemm path: out[m][o] = sum_k x[m][k] * W1[o][k] ----
    float (*As)[68]  = (float(*)[68])smem;
    float (*Ws)[132] = (float(*)[132])(smem + 32 * 68 * sizeof(float));
    int tx = t & 31;
    int ty = t >> 5;
    int row0 = (bid - NB) * 64;
    float acc[8][4] = {};
    for (int k0 = 0; k0 < 128; k0 += 32) {
        #pragma unroll
        for (int i = 0; i < 8; ++i) {
            int idx = t + i * 256;
            int r = idx >> 5, k = idx & 31;
            int gr = row0 + r;
            As[k][r] = (gr < N_NODES) ? x[gr * CH + k0 + k] : 0.0f;
        }
        #pragma unroll
        for (int i = 0; i < 16; ++i) {
            int idx = t + i * 256;
            int o = idx >> 5, k = idx & 31;
            Ws[k][o] = W1[o * CH + k0 + k];
        }
        __syncthreads();
        #pragma unroll
        for (int kk = 0; kk < 32; ++kk) {
            float a[8], w[4];
            #pragma unroll
            for (int j = 0; j < 8; ++j) a[j] = As[kk][ty * 8 + j];
            #pragma unroll
            for (int c = 0; c < 4; ++c) w[c] = Ws[kk][tx * 4 + c];
            #pragma unroll
            for (int j = 0; j < 8; ++j)
                #pragma unroll
                for (int c = 0; c < 4; ++c)
                    acc[j][c] += a[j] * w[c];
        }
        __syncthreads();
    }
    #pragma unroll
    for (int j = 0; j < 8; ++j) {
        int gr = row0 + ty * 8 + j;
        if (gr < N_NODES) {
            float4 v = make_float4(acc[j][0], acc[j][1], acc[j][2], acc[j][3]);
            *reinterpret_cast<float4*>(&out[gr * CH + tx * 4]) = v;
        }
    }
}

// ---------------------------------------------------------------------------
// K2: per-node totals + dinv + global exclusive prefix + cursor conversion.
// (round-4 proven, verbatim)
__global__ __launch_bounds__(256) void bofs_kernel(int* __restrict__ hist,
        const float* __restrict__ dhist, const int* __restrict__ pcs,
        int* __restrict__ tot, int* __restrict__ offs, float* __restrict__ dinv) {
    __shared__ int wred[4];
    __shared__ int wsum[4];
    __shared__ int base_sh;
    int blk = blockIdx.x, t = threadIdx.x;
    int lane = t & 63, wave = t >> 6;
    int bsum = 0;
    for (int i = t; i < blk * NB; i += 256) bsum += pcs[i];
    #pragma unroll
    for (int off = 32; off > 0; off >>= 1) bsum += __shfl_down(bsum, off, 64);
    if (lane == 0) wred[wave] = bsum;
    __syncthreads();
    if (t == 0) base_sh = wred[0] + wred[1] + wred[2] + wred[3];
    int n = blk * 256 + t;
    int v = 0;
    if (n < N_NODES) {
        float dsum = 0.0f;
        #pragma unroll 8
        for (int b = 0; b < NB; ++b) {
            v += hist[b * N_NODES + n];
            dsum += dhist[b * N_NODES + n];
        }
        tot[n] = v;
        dinv[n] = rsqrtf(dsum + 1.0f);            // +1 = self-loop weight
    }
    int s = v;
    #pragma unroll
    for (int off = 1; off < 64; off <<= 1) {
        int u = __shfl_up(s, off, 64);
        if (lane >= off) s += u;
    }
    if (lane == 63) wsum[wave] = s;
    __syncthreads();
    int wbase = 0;
    for (int i = 0; i < wave; ++i) wbase += wsum[i];
    if (n < N_NODES) {
        int run = base_sh + wbase + s - v;        // global exclusive prefix
        offs[n] = run;
        for (int b = 0; b < NB; ++b) {
            int h = hist[b * N_NODES + n];
            hist[b * N_NODES + n] = run;          // column -> start cursor
            run += h;
        }
    }
}

// ---------------------------------------------------------------------------
// K3: scatter edges into CSR order via LDS cursors; records carry the fully
// NORMALIZED value dinv[r]*w*dinv[c].  (round-4 proven, verbatim)
__global__ __launch_bounds__(256) void scatter_kernel(const int* __restrict__ ei,
        const float* __restrict__ ew, const float* __restrict__ dinv,
        const int* __restrict__ bofs, int2* __restrict__ erec) {
    __shared__ int cur[N_NODES];                 // 40 KB
    __shared__ float di[N_NODES];                // 40 KB
    int b = blockIdx.x, t = threadIdx.x;
    for (int i = t; i < N_NODES; i += 256) {
        cur[i] = bofs[b * N_NODES + i];
        di[i] = dinv[i];
    }
    __syncthreads();
    int e0 = b * EPB;
    for (int i = t; i < EPB; i += 256) {
        int e = e0 + i;
        int r = ei[e];
        int c = ei[N_EDGES + e];
        float v = di[r] * ew[e] * di[c];
        int p = atomicAdd(&cur[c], 1);           // LDS atomic
        erec[p] = make_int2(r, __float_as_int(v));
    }
}

// ---------------------------------------------------------------------------
// Forced 8-wide gather: 8 global_load_dwordx4 issued from one asm block with
// early-clobber outs — the allocator CANNOT re-serialize to 2-deep (the
// failure mode of rounds 5/6/9: VGPR stuck at 40).
#define GATHER8_ASM(F0,F1,F2,F3,F4,F5,F6,F7, P0,P1,P2,P3,P4,P5,P6,P7)        \
    asm volatile(                                                            \
        "global_load_dwordx4 %0, %8, off\n\t"                                \
        "global_load_dwordx4 %1, %9, off\n\t"                                \
        "global_load_dwordx4 %2, %10, off\n\t"                               \
        "global_load_dwordx4 %3, %11, off\n\t"                               \
        "global_load_dwordx4 %4, %12, off\n\t"                               \
        "global_load_dwordx4 %5, %13, off\n\t"                               \
        "global_load_dwordx4 %6, %14, off\n\t"                               \
        "global_load_dwordx4 %7, %15, off\n\t"                               \
        "s_waitcnt vmcnt(0)"                                                 \
        : "=&v"(F0), "=&v"(F1), "=&v"(F2), "=&v"(F3),                        \
          "=&v"(F4), "=&v"(F5), "=&v"(F6), "=&v"(F7)                         \
        : "v"(P0), "v"(P1), "v"(P2), "v"(P3),                                \
          "v"(P4), "v"(P5), "v"(P6), "v"(P7))

// ---------------------------------------------------------------------------
// K4: FUSED agg1 + gemm2. Round-4 structure (256 thr, 8 nodes/block) with:
// (a) records staged in LDS (ds_read, separate lgkmcnt queue, short latency);
// (b) asm-forced 8-deep gathers.
__global__ __launch_bounds__(256) void agg_gemm_kernel(const f32x4* __restrict__ xw,
        const int2* __restrict__ erec, const int* __restrict__ offs,
        const int* __restrict__ cnt, const float* __restrict__ dinv,
        const float* __restrict__ bias, const float* __restrict__ W2,
        float* __restrict__ out) {
    __shared__ float hs[8][128];                 // 4 KB relu'd h1 rows
    __shared__ int2 lrec[8][128];                // 8 KB staged records
    int l = threadIdx.x & 31;                    // channel quad
    int g = threadIdx.x >> 5;                    // node group 0..7
    int n = blockIdx.x * 8 + g;
    int start = offs[n];
    int num = cnt[n];
    int ns = num <= 128 ? num : 128;             // deg>128: astronomically rare
    for (int i = l; i < ns; i += 32)             // coalesced 256 B/group/iter;
        lrec[g][i] = erec[start + i];            // same-wave producer/consumer
    float d = dinv[n];
    float dd = d * d;
    f32x4 self = xw[(size_t)n * 32 + l];
    f32x4 acc = dd * self;
    int i = 0;
    for (; i + 8 <= ns; i += 8) {
        int2 r0 = lrec[g][i+0], r1 = lrec[g][i+1], r2 = lrec[g][i+2], r3 = lrec[g][i+3];
        int2 r4 = lrec[g][i+4], r5 = lrec[g][i+5], r6 = lrec[g][i+6], r7 = lrec[g][i+7];
        const f32x4 *p0 = xw + ((size_t)r0.x * 32 + l), *p1 = xw + ((size_t)r1.x * 32 + l);
        const f32x4 *p2 = xw + ((size_t)r2.x * 32 + l), *p3 = xw + ((size_t)r3.x * 32 + l);
        const f32x4 *p4 = xw + ((size_t)r4.x * 32 + l), *p5 = xw + ((size_t)r5.x * 32 + l);
        const f32x4 *p6 = xw + ((size_t)r6.x * 32 + l), *p7 = xw + ((size_t)r7.x * 32 + l);
        f32x4 f0, f1, f2, f3, f4, f5, f6, f7;
        GATHER8_ASM(f0, f1, f2, f3, f4, f5, f6, f7, p0, p1, p2, p3, p4, p5, p6, p7);
        acc += __int_as_float(r0.y) * f0;
        acc += __int_as_float(r1.y) * f1;
        acc += __int_as_float(r2.y) * f2;
        acc += __int_as_float(r3.y) * f3;
        acc += __int_as_float(r4.y) * f4;
        acc += __int_as_float(r5.y) * f5;
        acc += __int_as_float(r6.y) * f6;
        acc += __int_as_float(r7.y) * f7;
    }
    for (; i < num; ++i) {                       // tail (and deg>128 overflow)
        int2 r = (i < ns) ? lrec[g][i] : erec[start + i];
        f32x4 f = xw[(size_t)r.x * 32 + l];
        acc += __int_as_float(r.y) * f;
    }
    const f32x4 bb = ((const f32x4*)bias)[l];
    f32x4 h;
    h.x = fmaxf(acc.x + bb.x, 0.0f);
    h.y = fmaxf(acc.y + bb.y, 0.0f);
    h.z = fmaxf(acc.z + bb.z, 0.0f);
    h.w = fmaxf(acc.w + bb.w, 0.0f);
    *reinterpret_cast<f32x4*>(&hs[g][4 * l]) = h;
    __syncthreads();
    // ---- mini-GEMM: thread = (output channel o, row-group rg of 4 rows) ----
    int o = threadIdx.x & 127;
    int rg = threadIdx.x >> 7;                   // 0: rows 0-3, 1: rows 4-7
    const float4* w4p = reinterpret_cast<const float4*>(&W2[o * CH]);
    const float4* h0p = reinterpret_cast<const float4*>(&hs[rg * 4 + 0][0]);
    const float4* h1p = reinterpret_cast<const float4*>(&hs[rg * 4 + 1][0]);
    const float4* h2p = reinterpret_cast<const float4*>(&hs[rg * 4 + 2][0]);
    const float4* h3p = reinterpret_cast<const float4*>(&hs[rg * 4 + 3][0]);
    float a0 = 0.0f, a1 = 0.0f, a2 = 0.0f, a3 = 0.0f;
    #pragma unroll 8
    for (int k4 = 0; k4 < 32; ++k4) {
        float4 w = w4p[k4];                      // L2-hot W2 row
        float4 h0 = h0p[k4], h1 = h1p[k4], h2 = h2p[k4], h3 = h3p[k4];
        a0 += w.x * h0.x + w.y * h0.y + w.z * h0.z + w.w * h0.w;
        a1 += w.x * h1.x + w.y * h1.y + w.z * h1.z + w.w * h1.w;
        a2 += w.x * h2.x + w.y * h2.y + w.z * h2.z + w.w * h2.w;
        a3 += w.x * h3.x + w.y * h3.y + w.z * h3.z + w.w * h3.w;
    }
    int nb = blockIdx.x * 8 + rg * 4;
    out[(nb + 0) * CH + o] = a0;
    out[(nb + 1) * CH + o] = a1;
    out[(nb + 2) * CH + o] = a2;
    out[(nb + 3) * CH + o] = a3;
}

// ---------------------------------------------------------------------------
// K5: agg layer 2 — same LDS-records + asm-gather inner loop.
__global__ __launch_bounds__(256) void agg_kernel(const f32x4* __restrict__ xw,
        const int2* __restrict__ erec, const int* __restrict__ offs,
        const int* __restrict__ cnt, const float* __restrict__ dinv,
        const float* __restrict__ bias, f32x4* __restrict__ out4) {
    __shared__ int2 lrec[8][128];                // 8 KB staged records
    int l = threadIdx.x & 31;
    int g = threadIdx.x >> 5;
    int n = blockIdx.x * 8 + g;
    int start = offs[n];
    int num = cnt[n];
    int ns = num <= 128 ? num : 128;
    for (int i = l; i < ns; i += 32)
        lrec[g][i] = erec[start + i];
    float d = dinv[n];
    float dd = d * d;
    f32x4 self = xw[(size_t)n * 32 + l];
    f32x4 acc = dd * self;
    int i = 0;
    for (; i + 8 <= ns; i += 8) {
        int2 r0 = lrec[g][i+0], r1 = lrec[g][i+1], r2 = lrec[g][i+2], r3 = lrec[g][i+3];
        int2 r4 = lrec[g][i+4], r5 = lrec[g][i+5], r6 = lrec[g][i+6], r7 = lrec[g][i+7];
        const f32x4 *p0 = xw + ((size_t)r0.x * 32 + l), *p1 = xw + ((size_t)r1.x * 32 + l);
        const f32x4 *p2 = xw + ((size_t)r2.x * 32 + l), *p3 = xw + ((size_t)r3.x * 32 + l);
        const f32x4 *p4 = xw + ((size_t)r4.x * 32 + l), *p5 = xw + ((size_t)r5.x * 32 + l);
        const f32x4 *p6 = xw + ((size_t)r6.x * 32 + l), *p7 = xw + ((size_t)r7.x * 32 + l);
        f32x4 f0, f1, f2, f3, f4, f5, f6, f7;
        GATHER8_ASM(f0, f1, f2, f3, f4, f5, f6, f7, p0, p1, p2, p3, p4, p5, p6, p7);
        acc += __int_as_float(r0.y) * f0;
        acc += __int_as_float(r1.y) * f1;
        acc += __int_as_float(r2.y) * f2;
        acc += __int_as_float(r3.y) * f3;
        acc += __int_as_float(r4.y) * f4;
        acc += __int_as_float(r5.y) * f5;
        acc += __int_as_float(r6.y) * f6;
        acc += __int_as_float(r7.y) * f7;
    }
    for (; i < num; ++i) {
        int2 r = (i < ns) ? lrec[g][i] : erec[start + i];
        f32x4 f = xw[(size_t)r.x * 32 + l];
        acc += __int_as_float(r.y) * f;
    }
    const f32x4 bb = ((const f32x4*)bias)[l];
    f32x4 h;
    h.x = fmaxf(acc.x + bb.x, 0.0f);
    h.y = fmaxf(acc.y + bb.y, 0.0f);
    h.z = fmaxf(acc.z + bb.z, 0.0f);
    h.w = fmaxf(acc.w + bb.w, 0.0f);
    out4[(size_t)n * 32 + l] = h;
}

// ---------------------------------------------------------------------------
// K6: fused temporal conv + fc: one wave per node, lane handles ch l and l+64.
__global__ __launch_bounds__(256) void convfc_kernel(const float* __restrict__ h,
        const float* __restrict__ v, const float* __restrict__ c0,
        float* __restrict__ out, int N) {
    int n = blockIdx.x * 4 + (threadIdx.x >> 6);
    int l = threadIdx.x & 63;
    if (n >= N) return;
    const float* hn = h + n * CH;
    float v0a = v[l * 3 + 0],        v1a = v[l * 3 + 1],        v2a = v[l * 3 + 2];
    float v0b = v[(l + 64) * 3 + 0], v1b = v[(l + 64) * 3 + 1], v2b = v[(l + 64) * 3 + 2];
    float p = hn[l] * v1a + hn[l + 64] * v1b;
    if (n > 0)     p += hn[l - CH] * v0a + hn[l + 64 - CH] * v0b;
    if (n < N - 1) p += hn[l + CH] * v2a + hn[l + 64 + CH] * v2b;
    #pragma unroll
    for (int off = 32; off > 0; off >>= 1) p += __shfl_down(p, off, 64);
    if (l == 0) out[n] = p + *c0;
}

// ---------------------------------------------------------------------------
extern "C" void kernel_launch(void* const* d_in, const int* in_sizes, int n_in,
                              void* d_out, int out_size, void* d_ws, size_t ws_size,
                              hipStream_t stream) {
    const float* x       = (const float*)d_in[0];
    const int*   ei      = (const int*)d_in[1];
    const float* ew      = (const float*)d_in[2];
    const float* W1      = (const float*)d_in[3];
    const float* b1      = (const float*)d_in[4];
    const float* W2      = (const float*)d_in[5];
    const float* b2      = (const float*)d_in[6];
    const float* conv_w  = (const float*)d_in[7];
    const float* conv_b  = (const float*)d_in[8];
    const float* fc_w    = (const float*)d_in[9];
    const float* fc_b    = (const float*)d_in[10];
    float* out = (float*)d_out;

    float* bufA   = (float*)d_ws;                   // 1,280,000 f (xw1, later h2)
    float* bufB   = bufA + N_NODES * CH;            // 1,280,000 f (xw2)
    int2*  erec   = (int2*)(bufB + N_NODES * CH);   // 640,000 x 8B
    int*   hist   = (int*)(erec + N_EDGES);         // NB*10,000 i
    float* dhist  = (float*)(hist + NB * N_NODES);  // NB*10,000 f
    int*   pcs    = (int*)(dhist + NB * N_NODES);   // NCHUNK*NB i
    int*   tot    = pcs + NCHUNK * NB;              // 10,000 i
    int*   offs   = tot + N_NODES;                  // 10,000 i
    float* dinv   = (float*)(offs + N_NODES);       // 10,000 f
    float* vbuf   = dinv + N_NODES;                 // 384 f
    float* c0     = vbuf + 384;                     // 1 f

    const int gemm_grid = (N_NODES + 63) / 64;      // 157

    // K1: dual-hist (64) + gemm1 (157) + weight-fold (1), all data-independent
    fused_hist_gemm<<<NB + gemm_grid + 1, 256, 0, stream>>>(ei, ew, x, W1,
            hist, dhist, pcs, bufA, conv_w, conv_b, fc_w, fc_b, vbuf, c0);
    // K2: totals + dinv + prefix + cursor conversion
    bofs_kernel<<<NCHUNK, 256, 0, stream>>>(hist, dhist, pcs, tot, offs, dinv);
    // K3: normalized CSR scatter
    scatter_kernel<<<NB, 256, 0, stream>>>(ei, ew, dinv, hist, erec);
    // K4: agg1 + gemm2 fused (asm 8-deep gathers): bufA -> bufB
    agg_gemm_kernel<<<N_NODES / 8, 256, 0, stream>>>((const f32x4*)bufA, erec, offs,
            tot, dinv, b1, W2, bufB);
    // K5: agg layer 2 (asm 8-deep gathers): bufB -> bufA
    agg_kernel<<<N_NODES / 8, 256, 0, stream>>>((const f32x4*)bufB, erec, offs, tot,
                                                dinv, b2, (f32x4*)bufA);
    // K6: fused temporal conv + fc
    convfc_kernel<<<(N_NODES + 3) / 4, 256, 0, stream>>>(bufA, vbuf, c0, out, N_NODES);
}